// Round 5
// baseline (158.640 us; speedup 1.0000x reference)
//
#include <hip/hip_runtime.h>

typedef unsigned short u16;
typedef unsigned int u32;
typedef __bf16 bfx8 __attribute__((ext_vector_type(8)));
typedef u16 u16x8 __attribute__((ext_vector_type(8)));
typedef float f32x4 __attribute__((ext_vector_type(4)));

#define HIDDEN 1024
#define HEADS 16
#define HDIM 64
#define SEQ 2048
#define LOG2E 1.44269504f

__device__ __forceinline__ u16 f2bf(float f) {
  u32 u = __builtin_bit_cast(u32, f);
  u += 0x7fffu + ((u >> 16) & 1u);
  return (u16)(u >> 16);
}
__device__ __forceinline__ float bf2f(u16 v) {
  u32 u = ((u32)v) << 16;
  return __builtin_bit_cast(float, u);
}

#define GLOAD_LDS16(g, l)                                                       \
  __builtin_amdgcn_global_load_lds(                                             \
      (const __attribute__((address_space(1))) void*)(g),                       \
      (__attribute__((address_space(3))) void*)(l), 16, 0, 0)

#define MFMA16(a, b, c) __builtin_amdgcn_mfma_f32_16x16x32_bf16(a, b, c, 0, 0, 0)

// ---------------- cast hidden fp32 -> bf16 ----------------
__global__ __launch_bounds__(256) void cast_bf16_kernel(
    const float* __restrict__ src, u16* __restrict__ dst, int n4) {
  int idx = blockIdx.x * blockDim.x + threadIdx.x;
  int stride = gridDim.x * blockDim.x;
  for (int i = idx; i < n4; i += stride) {
    float4 v = ((const float4*)src)[i];
    ushort4 o;
    o.x = f2bf(v.x); o.y = f2bf(v.y); o.z = f2bf(v.z); o.w = f2bf(v.w);
    ((ushort4*)dst)[i] = o;
  }
}

// ------------- transpose-cast 4 weights W[k][n] fp32 -> Wt[n][k] bf16 -------------
__global__ __launch_bounds__(256) void transpose_cast4_kernel(
    const float* __restrict__ W0, const float* __restrict__ W1,
    const float* __restrict__ W2, const float* __restrict__ W3,
    u16* __restrict__ dstbase) {
  __shared__ u16 tile[64][65];
  const float* W = blockIdx.z == 0 ? W0 : blockIdx.z == 1 ? W1
                  : blockIdx.z == 2 ? W2 : W3;
  u16* Wt = dstbase + (size_t)blockIdx.z * HIDDEN * HIDDEN;
  const int kt = blockIdx.y * 64, nt = blockIdx.x * 64;
  const int t = threadIdx.x;
#pragma unroll
  for (int it = 0; it < 16; ++it) {
    int kl = it * 4 + (t >> 6), nl = t & 63;
    tile[kl][nl] = f2bf(W[(size_t)(kt + kl) * HIDDEN + nt + nl]);
  }
  __syncthreads();
#pragma unroll
  for (int it = 0; it < 16; ++it) {
    int nl = it * 4 + (t >> 6), kl = t & 63;
    Wt[(size_t)(nt + nl) * HIDDEN + kt + kl] = tile[kl][nl];
  }
}

// ---------------- V transpose: [bh][s][64] bf16 -> [bh][64][s] ----------------
__global__ __launch_bounds__(256) void vtrans_kernel(
    const u16* __restrict__ vin, u16* __restrict__ vout) {
  __shared__ u16 t[64][65];
  const int bh = blockIdx.y;
  const int s0 = blockIdx.x * 64;
  const u16* src = vin + ((size_t)bh * SEQ + s0) * HDIM;
  u16* dst = vout + (size_t)bh * HDIM * SEQ + s0;
  const int tr = threadIdx.x >> 3;        // 0..31
  const int tc = (threadIdx.x & 7) * 8;   // 0,8,..,56
#pragma unroll
  for (int it = 0; it < 2; ++it) {
    const int sr = it * 32 + tr;
    u16x8 v = *(const u16x8*)(src + (size_t)sr * HDIM + tc);
#pragma unroll
    for (int e = 0; e < 8; ++e) t[sr][tc + e] = v[e];
  }
  __syncthreads();
#pragma unroll
  for (int it = 0; it < 2; ++it) {
    const int dr = it * 32 + tr;   // d index
    u16x8 o;
#pragma unroll
    for (int e = 0; e < 8; ++e) o[e] = t[tc + e][dr];
    *(u16x8*)(dst + (size_t)dr * SEQ + tc) = o;
  }
}

// =================================================================
// 128x128, BK=64, single-buffer m97-structure core.
// LDS in FRAGMENT ORDER (proven 0-conflict in round 4): subtile
// (16 rows x 32 kcols) stored contiguously, elem = sub*512 + lane*8,
// where sub = kh*8 + rowsub. Staged via global_load_lds with the
// per-lane global address pre-permuted (lane l -> row l&15, kslot l>>4).
// =================================================================
__device__ __forceinline__ void gemm_core64(const u16* __restrict__ A,
                                            const u16* __restrict__ Bt,
                                            int m0, int n0, u16* As, u16* Bs,
                                            f32x4 acc[4][4]) {
  const int lane = threadIdx.x & 63;
  const int wave = threadIdx.x >> 6;  // 0..3
  const int wm = wave >> 1, wn = wave & 1;
  const int li = lane & 15, lg = lane >> 4;
  const f32x4 zero = {0.f, 0.f, 0.f, 0.f};
#pragma unroll
  for (int i = 0; i < 4; ++i)
#pragma unroll
    for (int j = 0; j < 4; ++j) acc[i][j] = zero;

  const u16* Ag = A + (size_t)m0 * HIDDEN;
  const u16* Bg = Bt + (size_t)n0 * HIDDEN;

  for (int kt = 0; kt < HIDDEN; kt += 64) {
    __syncthreads();  // previous iteration's LDS reads done
#pragma unroll
    for (int j = 0; j < 4; ++j) {
      const int sub = wave * 4 + j;      // 0..15
      const int kh = sub >> 3, rs = sub & 7;
      const size_t goff = (size_t)(rs * 16 + li) * HIDDEN + kt + kh * 32 + lg * 8;
      GLOAD_LDS16(Ag + goff, As + sub * 512);
      GLOAD_LDS16(Bg + goff, Bs + sub * 512);
    }
    __syncthreads();  // drains vmcnt -> staged data visible
#pragma unroll
    for (int ks = 0; ks < 2; ++ks) {
      bfx8 af[4], bf[4];
#pragma unroll
      for (int f = 0; f < 4; ++f) {
        af[f] = *(const bfx8*)(As + (ks * 8 + wm * 4 + f) * 512 + lane * 8);
        bf[f] = *(const bfx8*)(Bs + (ks * 8 + wn * 4 + f) * 512 + lane * 8);
      }
#pragma unroll
      for (int fm = 0; fm < 4; ++fm)
#pragma unroll
        for (int fn = 0; fn < 4; ++fn)
          acc[fm][fn] = MFMA16(af[fm], bf[fn], acc[fm][fn]);
    }
  }
}

// ---------------- QKV projection + epilogue ----------------
// vmode=1: V stored row-major [bh][s][d] (coalesced; transposed later).
// vmode=0: legacy direct V^T scatter (ws too small fallback).
__global__ __launch_bounds__(256) void gemm_qkv_kernel(
    const u16* __restrict__ A, const u16* __restrict__ Bt,
    const float* __restrict__ bq, const float* __restrict__ bk,
    const float* __restrict__ bv, u16* __restrict__ qo, u16* __restrict__ ko,
    u16* __restrict__ vo, int vmode) {
  __shared__ alignas(16) u16 As[16 * 512];
  __shared__ alignas(16) u16 Bs[16 * 512];
  f32x4 acc[4][4];
  // 768 blocks = 8 XCDs x 96; n-fastest within XCD (A-panel reuse)
  const int bid = blockIdx.x;
  const int wid = (bid & 7) * 96 + (bid >> 3);
  const int bm = wid / 24, bn = wid % 24;
  const int m0 = bm * 128, n0 = bn * 128;
  gemm_core64(A, Bt, m0, n0, As, Bs, acc);

  const int lane = threadIdx.x & 63;
  const int wave = threadIdx.x >> 6;
  const int wm = wave >> 1, wn = wave & 1;
  const int li = lane & 15, lg = lane >> 4;
#pragma unroll
  for (int fn = 0; fn < 4; ++fn) {
    const int n = n0 + wn * 64 + fn * 16 + li;
    const int which = n >> 10;   // 0=q 1=k 2=v
    const int nn = n & 1023;
    const float bias = (which == 0 ? bq : which == 1 ? bk : bv)[nn];
    const int hh = nn >> 6, d = nn & 63;
    u16* base = which == 0 ? qo : which == 1 ? ko : vo;
#pragma unroll
    for (int fm = 0; fm < 4; ++fm) {
#pragma unroll
      for (int r = 0; r < 4; ++r) {
        const int m = m0 + wm * 64 + fm * 16 + lg * 4 + r;
        const int bb = m >> 11, s = m & (SEQ - 1);
        const int bh = bb * HEADS + hh;
        const u16 val = f2bf(acc[fm][fn][r] + bias);
        if (which == 2 && !vmode)
          vo[((size_t)bh * HDIM + d) * SEQ + s] = val;   // direct V^T scatter
        else
          base[((size_t)bh * SEQ + s) * HDIM + d] = val;  // coalesced rows
      }
    }
  }
}

// ---------------- output projection ----------------
__global__ __launch_bounds__(256) void gemm_out_kernel(
    const u16* __restrict__ A, const u16* __restrict__ Bt,
    const float* __restrict__ bo, float* __restrict__ out) {
  __shared__ alignas(16) u16 As[16 * 512];
  __shared__ alignas(16) u16 Bs[16 * 512];
  f32x4 acc[4][4];
  // 256 blocks = 8 XCDs x 32
  const int bid = blockIdx.x;
  const int wid = (bid & 7) * 32 + (bid >> 3);
  const int bm = wid / 8, bn = wid % 8;
  const int m0 = bm * 128, n0 = bn * 128;
  gemm_core64(A, Bt, m0, n0, As, Bs, acc);

  const int lane = threadIdx.x & 63;
  const int wave = threadIdx.x >> 6;
  const int wm = wave >> 1, wn = wave & 1;
  const int li = lane & 15, lg = lane >> 4;
#pragma unroll
  for (int fm = 0; fm < 4; ++fm)
#pragma unroll
    for (int fn = 0; fn < 4; ++fn) {
      const int n = n0 + wn * 64 + fn * 16 + li;
      const float bias = bo[n];
#pragma unroll
      for (int r = 0; r < 4; ++r) {
        const int m = m0 + wm * 64 + fm * 16 + lg * 4 + r;
        out[(size_t)m * HIDDEN + n] = acc[fm][fn][r] + bias;
      }
    }
}

// ---------------- sliding-window + global-token attention (v2) ----------------
#define ATTN_STEP(KFC, KFN, PAR)                                                 \
  {                                                                             \
    const int j0 = wlo + (c << 5);                                              \
    int sidx = j0 + lg * 8;                                                     \
    if (sidx > SEQ - 8) sidx = SEQ - 8;                                         \
    const bfx8 vf0 = *(const bfx8*)(vb + (size_t)(li) * SEQ + sidx);            \
    const bfx8 vf1 = *(const bfx8*)(vb + (size_t)(16 + li) * SEQ + sidx);       \
    const bfx8 vf2 = *(const bfx8*)(vb + (size_t)(32 + li) * SEQ + sidx);       \
    const bfx8 vf3 = *(const bfx8*)(vb + (size_t)(48 + li) * SEQ + sidx);       \
    if (c + 1 < nc) {                                                           \
      const int j1 = j0 + 32;                                                   \
      int ja = j1 + li;      if (ja > SEQ - 1) ja = SEQ - 1;                    \
      int jb = j1 + 16 + li; if (jb > SEQ - 1) jb = SEQ - 1;                    \
      KFN[0] = *(const bfx8*)(kb + (size_t)ja * HDIM + lg * 8);                 \
      KFN[1] = *(const bfx8*)(kb + (size_t)ja * HDIM + 32 + lg * 8);            \
      KFN[2] = *(const bfx8*)(kb + (size_t)jb * HDIM + lg * 8);                 \
      KFN[3] = *(const bfx8*)(kb + (size_t)jb * HDIM + 32 + lg * 8);            \
    }                                                                           \
    f32x4 s0 = zero, s1 = zero;                                                 \
    s0 = MFMA16(qa[0], KFC[0], s0);                                             \
    s0 = MFMA16(qa[1], KFC[1], s0);                                             \
    s1 = MFMA16(qa[0], KFC[2], s1);                                             \
    s1 = MFMA16(qa[1], KFC[3], s1);                                             \
    const bool interior = (j0 >= i0 + 15 - half) && (j0 + 31 <= i0 + half) &&   \
                          (j0 + 31 <= SEQ - 1);                                 \
    if (interior) {                                                             \
      _Pragma("unroll") for (int r = 0; r < 4; ++r) {                           \
        const float p0 = exp2f(s0[r] * SCL);                                    \
        const float p1 = exp2f(s1[r] * SCL);                                    \
        lr[r] += p0 + p1;                                                       \
        P[PAR][lg * 4 + r][li] = f2bf(p0);                                      \
        P[PAR][lg * 4 + r][16 + li] = f2bf(p1);                                 \
      }                                                                         \
    } else {                                                                    \
      _Pragma("unroll") for (int r = 0; r < 4; ++r) {                           \
        const int i = i0 + lg * 4 + r;                                          \
        const int ja = j0 + li, jb = j0 + 16 + li;                              \
        int da = i - ja; if (da < 0) da = -da;                                  \
        int db = i - jb; if (db < 0) db = -db;                                  \
        const bool oka = (ja <= SEQ - 1) && (da <= half || ja == 0);            \
        const bool okb = (jb <= SEQ - 1) && (db <= half);                       \
        const float p0 = exp2f(fmaf(s0[r], SCL, oka ? 0.f : -1e5f));            \
        const float p1 = exp2f(fmaf(s1[r], SCL, okb ? 0.f : -1e5f));            \
        lr[r] += p0 + p1;                                                       \
        P[PAR][lg * 4 + r][li] = f2bf(p0);                                      \
        P[PAR][lg * 4 + r][16 + li] = f2bf(p1);                                 \
      }                                                                         \
    }                                                                           \
    const bfx8 pa = *(const bfx8*)(&P[PAR][li][lg * 8]);                        \
    ctxa[0] = MFMA16(pa, vf0, ctxa[0]);                                         \
    ctxa[1] = MFMA16(pa, vf1, ctxa[1]);                                         \
    ctxa[2] = MFMA16(pa, vf2, ctxa[2]);                                         \
    ctxa[3] = MFMA16(pa, vf3, ctxa[3]);                                         \
  }

__global__ __launch_bounds__(64) void attn_kernel(
    const u16* __restrict__ q, const u16* __restrict__ k,
    const u16* __restrict__ vt, u16* __restrict__ ctx,
    const int* __restrict__ wsz) {
  const int lane = threadIdx.x;
  const int li = lane & 15, lg = lane >> 4;
  const int bid = blockIdx.x;
  const int wid = (bid & 7) * 512 + (bid >> 3);
  const int qt = wid & 127;
  const int h = (wid >> 7) & 15;
  const int b = wid >> 11;
  const int i0 = qt * 16;
  const int bh = b * HEADS + h;
  const int half = wsz[0] >> 1;
  const float SCL = 0.125f * LOG2E;

  __shared__ alignas(16) u16 P[2][16][40];

  const u16* qb = q + (size_t)bh * SEQ * HDIM;
  const u16* kb = k + (size_t)bh * SEQ * HDIM;
  const u16* vb = vt + (size_t)bh * HDIM * SEQ;

  bfx8 qa[2];
#pragma unroll
  for (int ks = 0; ks < 2; ++ks)
    qa[ks] = *(const bfx8*)(qb + (size_t)(i0 + li) * HDIM + ks * 32 + lg * 8);

  int wlo = i0 - half; if (wlo < 0) wlo = 0; wlo &= ~31;
  int whi = i0 + 15 + half; if (whi > SEQ - 1) whi = SEQ - 1;
  const int nc = ((whi - wlo) >> 5) + 1;

  float lr[4] = {0.f, 0.f, 0.f, 0.f};
  f32x4 ctxa[4];
  const f32x4 zero = {0.f, 0.f, 0.f, 0.f};
#pragma unroll
  for (int dt = 0; dt < 4; ++dt) ctxa[dt] = zero;

  bfx8 kfA[4], kfB[4];
  {
    int ja = wlo + li;      if (ja > SEQ - 1) ja = SEQ - 1;
    int jb = wlo + 16 + li; if (jb > SEQ - 1) jb = SEQ - 1;
    kfA[0] = *(const bfx8*)(kb + (size_t)ja * HDIM + lg * 8);
    kfA[1] = *(const bfx8*)(kb + (size_t)ja * HDIM + 32 + lg * 8);
    kfA[2] = *(const bfx8*)(kb + (size_t)jb * HDIM + lg * 8);
    kfA[3] = *(const bfx8*)(kb + (size_t)jb * HDIM + 32 + lg * 8);
  }

  int c = 0;
  while (true) {
    ATTN_STEP(kfA, kfB, 0); if (++c >= nc) break;
    ATTN_STEP(kfB, kfA, 1); if (++c >= nc) break;
  }

#pragma unroll
  for (int r = 0; r < 4; ++r) {
    lr[r] += __shfl_xor(lr[r], 1);
    lr[r] += __shfl_xor(lr[r], 2);
    lr[r] += __shfl_xor(lr[r], 4);
    lr[r] += __shfl_xor(lr[r], 8);
  }

  if (wlo > 0) {
    const bfx8 k0a = *(const bfx8*)(kb + lg * 8);
    const bfx8 k0b = *(const bfx8*)(kb + 32 + lg * 8);
    float sg = 0.f;
#pragma unroll
    for (int e = 0; e < 8; ++e)
      sg += (float)qa[0][e] * (float)k0a[e] + (float)qa[1][e] * (float)k0b[e];
    sg += __shfl_xor(sg, 16);
    sg += __shfl_xor(sg, 32);
    const float pg = exp2f(sg * SCL);
    float v0[4];
#pragma unroll
    for (int dt = 0; dt < 4; ++dt) v0[dt] = bf2f(vb[(size_t)(dt * 16 + li) * SEQ]);
#pragma unroll
    for (int r = 0; r < 4; ++r) {
      const float pq = __shfl(pg, lg * 4 + r);
      lr[r] += pq;
#pragma unroll
      for (int dt = 0; dt < 4; ++dt) ctxa[dt][r] += pq * v0[dt];
    }
  }

#pragma unroll
  for (int r = 0; r < 4; ++r) {
    const float inv = 1.0f / lr[r];
    const int i = i0 + lg * 4 + r;
    const size_t base = ((size_t)b * SEQ + i) * HIDDEN + h * HDIM;
#pragma unroll
    for (int dt = 0; dt < 4; ++dt)
      ctx[base + dt * 16 + li] = f2bf(ctxa[dt][r] * inv);
  }
}

extern "C" void kernel_launch(void* const* d_in, const int* in_sizes, int n_in,
                              void* d_out, int out_size, void* d_ws, size_t ws_size,
                              hipStream_t stream) {
  const float* hs = (const float*)d_in[0];
  const float* Wq = (const float*)d_in[1];
  const float* bq = (const float*)d_in[2];
  const float* Wk = (const float*)d_in[3];
  const float* bk = (const float*)d_in[4];
  const float* Wv = (const float*)d_in[5];
  const float* bv = (const float*)d_in[6];
  const float* Wo = (const float*)d_in[7];
  const float* bo = (const float*)d_in[8];
  const int* wsz  = (const int*)d_in[9];
  float* out = (float*)d_out;

  const int BS = in_sizes[0] / HIDDEN;  // B*S = 4096
  (void)n_in; (void)out_size;

  u16* ws    = (u16*)d_ws;
  u16* hsb   = ws;                                  // [BS][1024] (reused as ctx)
  u16* wqkvt = hsb + (size_t)BS * HIDDEN;           // [3072][1024]
  u16* wot   = wqkvt + (size_t)3 * HIDDEN * HIDDEN; // [1024][1024]
  u16* qb    = wot + (size_t)HIDDEN * HIDDEN;       // [B*H][S][64]
  u16* kb    = qb + (size_t)BS * HIDDEN;
  u16* vtb   = kb + (size_t)BS * HIDDEN;            // [B*H][64][S]
  u16* vtmp  = vtb + (size_t)BS * HIDDEN;           // [B*H][S][64] (if ws allows)
  u16* ctxb  = hsb;

  const size_t need = ((size_t)4 * BS * HIDDEN + (size_t)4 * HIDDEN * HIDDEN +
                       (size_t)BS * HIDDEN) * sizeof(u16);
  const int vmode = (ws_size >= need) ? 1 : 0;   // deterministic per-harness

  cast_bf16_kernel<<<dim3(1024), dim3(256), 0, stream>>>(hs, hsb, BS * HIDDEN / 4);
  transpose_cast4_kernel<<<dim3(16, 16, 4), dim3(256), 0, stream>>>(Wq, Wk, Wv, Wo, wqkvt);

  gemm_qkv_kernel<<<dim3(768), dim3(256), 0, stream>>>(
      hsb, wqkvt, bq, bk, bv, qb, kb, vmode ? vtmp : vtb, vmode);

  if (vmode)
    vtrans_kernel<<<dim3(SEQ / 64, BS / SEQ * HEADS), dim3(256), 0, stream>>>(vtmp, vtb);

  attn_kernel<<<dim3(4096), dim3(64), 0, stream>>>(qb, kb, vtb, ctxb, wsz);

  gemm_out_kernel<<<dim3(256), dim3(256), 0, stream>>>(ctxb, wot, bo, out);
}

// Round 6
// 144.333 us; speedup vs baseline: 1.0991x; 1.0991x over previous
//
#include <hip/hip_runtime.h>

typedef unsigned short u16;
typedef unsigned int u32;
typedef __bf16 bfx8 __attribute__((ext_vector_type(8)));
typedef u16 u16x8 __attribute__((ext_vector_type(8)));
typedef float f32x4 __attribute__((ext_vector_type(4)));

#define HIDDEN 1024
#define HEADS 16
#define HDIM 64
#define SEQ 2048
#define LOG2E 1.44269504f

__device__ __forceinline__ u16 f2bf(float f) {
  u32 u = __builtin_bit_cast(u32, f);
  u += 0x7fffu + ((u >> 16) & 1u);
  return (u16)(u >> 16);
}
__device__ __forceinline__ float bf2f(u16 v) {
  u32 u = ((u32)v) << 16;
  return __builtin_bit_cast(float, u);
}

#define GLOAD_LDS16(g, l)                                                       \
  __builtin_amdgcn_global_load_lds(                                             \
      (const __attribute__((address_space(1))) void*)(g),                       \
      (__attribute__((address_space(3))) void*)(l), 16, 0, 0)

#define MFMA16(a, b, c) __builtin_amdgcn_mfma_f32_16x16x32_bf16(a, b, c, 0, 0, 0)

// ---------------- cast hidden fp32 -> bf16 ----------------
__global__ __launch_bounds__(256) void cast_bf16_kernel(
    const float* __restrict__ src, u16* __restrict__ dst, int n4) {
  int idx = blockIdx.x * blockDim.x + threadIdx.x;
  int stride = gridDim.x * blockDim.x;
  for (int i = idx; i < n4; i += stride) {
    float4 v = ((const float4*)src)[i];
    ushort4 o;
    o.x = f2bf(v.x); o.y = f2bf(v.y); o.z = f2bf(v.z); o.w = f2bf(v.w);
    ((ushort4*)dst)[i] = o;
  }
}

// ------------- transpose-cast 4 weights W[k][n] fp32 -> Wt[n][k] bf16 -------------
__global__ __launch_bounds__(256) void transpose_cast4_kernel(
    const float* __restrict__ W0, const float* __restrict__ W1,
    const float* __restrict__ W2, const float* __restrict__ W3,
    u16* __restrict__ dstbase) {
  __shared__ u16 tile[64][65];
  const float* W = blockIdx.z == 0 ? W0 : blockIdx.z == 1 ? W1
                  : blockIdx.z == 2 ? W2 : W3;
  u16* Wt = dstbase + (size_t)blockIdx.z * HIDDEN * HIDDEN;
  const int kt = blockIdx.y * 64, nt = blockIdx.x * 64;
  const int t = threadIdx.x;
#pragma unroll
  for (int it = 0; it < 16; ++it) {
    int kl = it * 4 + (t >> 6), nl = t & 63;
    tile[kl][nl] = f2bf(W[(size_t)(kt + kl) * HIDDEN + nt + nl]);
  }
  __syncthreads();
#pragma unroll
  for (int it = 0; it < 16; ++it) {
    int nl = it * 4 + (t >> 6), kl = t & 63;
    Wt[(size_t)(nt + nl) * HIDDEN + kt + kl] = tile[kl][nl];
  }
}

// ---------------- V transpose: [bh][s][64] bf16 -> [bh][64][s] ----------------
__global__ __launch_bounds__(256) void vtrans_kernel(
    const u16* __restrict__ vin, u16* __restrict__ vout) {
  __shared__ u16 t[64][65];
  const int bh = blockIdx.y;
  const int s0 = blockIdx.x * 64;
  const u16* src = vin + ((size_t)bh * SEQ + s0) * HDIM;
  u16* dst = vout + (size_t)bh * HDIM * SEQ + s0;
  const int tr = threadIdx.x >> 3;        // 0..31
  const int tc = (threadIdx.x & 7) * 8;   // 0,8,..,56
#pragma unroll
  for (int it = 0; it < 2; ++it) {
    const int sr = it * 32 + tr;
    u16x8 v = *(const u16x8*)(src + (size_t)sr * HDIM + tc);
#pragma unroll
    for (int e = 0; e < 8; ++e) t[sr][tc + e] = v[e];
  }
  __syncthreads();
#pragma unroll
  for (int it = 0; it < 2; ++it) {
    const int dr = it * 32 + tr;   // d index
    u16x8 o;
#pragma unroll
    for (int e = 0; e < 8; ++e) o[e] = t[tc + e][dr];
    *(u16x8*)(dst + (size_t)dr * SEQ + tc) = o;
  }
}

// =================================================================
// 128x128, BK=32, 2-barrier core (round-2 structure, measured best)
// with FRAGMENT-ORDER LDS (round-4, proven 0 bank conflicts):
// subtile (16 rows x 32 kcols) stored contiguously; fragment read =
// base + subtile*512 + lane*8 (quarter-wave reads 256 contiguous B).
// Staged via global_load_lds, per-lane GLOBAL address pre-permuted
// (lane l -> row l&15, kslot l>>4), LDS dest linear.
// =================================================================
__device__ __forceinline__ void gemm_core32(const u16* __restrict__ A,
                                            const u16* __restrict__ Bt,
                                            int m0, int n0, u16* As, u16* Bs,
                                            f32x4 acc[4][4]) {
  const int lane = threadIdx.x & 63;
  const int wave = threadIdx.x >> 6;  // 0..3
  const int wm = wave >> 1, wn = wave & 1;
  const int li = lane & 15, lg = lane >> 4;
  const f32x4 zero = {0.f, 0.f, 0.f, 0.f};
#pragma unroll
  for (int i = 0; i < 4; ++i)
#pragma unroll
    for (int j = 0; j < 4; ++j) acc[i][j] = zero;

  // per-lane permuted global bases (subtiles wave*2, wave*2+1)
  const u16* gA0 = A + ((size_t)m0 + wave * 32 + li) * HIDDEN + lg * 8;
  const u16* gB0 = Bt + ((size_t)n0 + wave * 32 + li) * HIDDEN + lg * 8;
  u16* lA = As + wave * 2 * 512;  // wave-uniform LDS dests
  u16* lB = Bs + wave * 2 * 512;

  for (int kt = 0; kt < HIDDEN; kt += 32) {
    __syncthreads();  // previous iteration's LDS reads done
    GLOAD_LDS16(gA0 + kt, lA);
    GLOAD_LDS16(gA0 + 16 * HIDDEN + kt, lA + 512);
    GLOAD_LDS16(gB0 + kt, lB);
    GLOAD_LDS16(gB0 + 16 * HIDDEN + kt, lB + 512);
    __syncthreads();  // drains vmcnt -> staged data visible
    bfx8 af[4], bf[4];
#pragma unroll
    for (int f = 0; f < 4; ++f) {
      af[f] = *(const bfx8*)(As + (wm * 4 + f) * 512 + lane * 8);
      bf[f] = *(const bfx8*)(Bs + (wn * 4 + f) * 512 + lane * 8);
    }
#pragma unroll
    for (int fm = 0; fm < 4; ++fm)
#pragma unroll
      for (int fn = 0; fn < 4; ++fn)
        acc[fm][fn] = MFMA16(af[fm], bf[fn], acc[fm][fn]);
  }
}

// ---------------- QKV projection + epilogue ----------------
// vmode=1: V stored row-major [bh][s][d] (coalesced; transposed later).
// vmode=0: legacy direct V^T scatter (ws too small fallback).
__global__ __launch_bounds__(256) void gemm_qkv_kernel(
    const u16* __restrict__ A, const u16* __restrict__ Bt,
    const float* __restrict__ bq, const float* __restrict__ bk,
    const float* __restrict__ bv, u16* __restrict__ qo, u16* __restrict__ ko,
    u16* __restrict__ vo, int vmode) {
  __shared__ alignas(16) u16 As[8 * 512];
  __shared__ alignas(16) u16 Bs[8 * 512];
  f32x4 acc[4][4];
  // grid dim3(24,32): x=n fastest; 24%8==0 -> each XCD sees a fixed set of
  // 3 n-panels (768KB weights, L2-resident) for every m-row.
  const int m0 = blockIdx.y * 128, n0 = blockIdx.x * 128;
  gemm_core32(A, Bt, m0, n0, As, Bs, acc);

  const int lane = threadIdx.x & 63;
  const int wave = threadIdx.x >> 6;
  const int wm = wave >> 1, wn = wave & 1;
  const int li = lane & 15, lg = lane >> 4;
#pragma unroll
  for (int fn = 0; fn < 4; ++fn) {
    const int n = n0 + wn * 64 + fn * 16 + li;
    const int which = n >> 10;   // 0=q 1=k 2=v
    const int nn = n & 1023;
    const float bias = (which == 0 ? bq : which == 1 ? bk : bv)[nn];
    const int hh = nn >> 6, d = nn & 63;
    u16* base = which == 0 ? qo : which == 1 ? ko : vo;
#pragma unroll
    for (int fm = 0; fm < 4; ++fm) {
#pragma unroll
      for (int r = 0; r < 4; ++r) {
        const int m = m0 + wm * 64 + fm * 16 + lg * 4 + r;
        const int bb = m >> 11, s = m & (SEQ - 1);
        const int bh = bb * HEADS + hh;
        const u16 val = f2bf(acc[fm][fn][r] + bias);
        if (which == 2 && !vmode)
          vo[((size_t)bh * HDIM + d) * SEQ + s] = val;   // direct V^T scatter
        else
          base[((size_t)bh * SEQ + s) * HDIM + d] = val;  // coalesced rows
      }
    }
  }
}

// ---------------- output projection: 128x64 tile, 2 blocks/CU ----------------
__global__ __launch_bounds__(256) void gemm_out_kernel(
    const u16* __restrict__ A, const u16* __restrict__ Bt,
    const float* __restrict__ bo, float* __restrict__ out) {
  __shared__ alignas(16) u16 As[8 * 512];   // 128 rows x 32 k
  __shared__ alignas(16) u16 Bs[4 * 512];   // 64 rows x 32 k
  const int lane = threadIdx.x & 63;
  const int wave = threadIdx.x >> 6;  // 0..3
  const int wm = wave >> 1, wn = wave & 1;
  const int li = lane & 15, lg = lane >> 4;
  // grid dim3(16,32): x=n fastest; 16%8==0 -> per-XCD B footprint 2 panels
  // (256KB), L2-resident.
  const int m0 = blockIdx.y * 128, n0 = blockIdx.x * 64;

  f32x4 acc[4][2];
  const f32x4 zero = {0.f, 0.f, 0.f, 0.f};
#pragma unroll
  for (int i = 0; i < 4; ++i) { acc[i][0] = zero; acc[i][1] = zero; }

  for (int kt = 0; kt < HIDDEN; kt += 32) {
    __syncthreads();
#pragma unroll
    for (int j = 0; j < 3; ++j) {
      const int g = wave * 3 + j;  // 0..11: 0-7 = A subtiles, 8-11 = B subtiles
      if (g < 8) {
        GLOAD_LDS16(A + ((size_t)m0 + g * 16 + li) * HIDDEN + kt + lg * 8,
                    As + g * 512);
      } else {
        GLOAD_LDS16(Bt + ((size_t)n0 + (g - 8) * 16 + li) * HIDDEN + kt + lg * 8,
                    Bs + (g - 8) * 512);
      }
    }
    __syncthreads();
    bfx8 af[4], bf[2];
#pragma unroll
    for (int f = 0; f < 4; ++f)
      af[f] = *(const bfx8*)(As + (wm * 4 + f) * 512 + lane * 8);
#pragma unroll
    for (int f = 0; f < 2; ++f)
      bf[f] = *(const bfx8*)(Bs + (wn * 2 + f) * 512 + lane * 8);
#pragma unroll
    for (int fm = 0; fm < 4; ++fm)
#pragma unroll
      for (int fn = 0; fn < 2; ++fn)
        acc[fm][fn] = MFMA16(af[fm], bf[fn], acc[fm][fn]);
  }

#pragma unroll
  for (int fm = 0; fm < 4; ++fm)
#pragma unroll
    for (int fn = 0; fn < 2; ++fn) {
      const int n = n0 + wn * 32 + fn * 16 + li;
      const float bias = bo[n];
#pragma unroll
      for (int r = 0; r < 4; ++r) {
        const int m = m0 + wm * 64 + fm * 16 + lg * 4 + r;
        out[(size_t)m * HIDDEN + n] = acc[fm][fn][r] + bias;
      }
    }
}

// ---------------- sliding-window + global-token attention (v2) ----------------
#define ATTN_STEP(KFC, KFN, PAR)                                                 \
  {                                                                             \
    const int j0 = wlo + (c << 5);                                              \
    int sidx = j0 + lg * 8;                                                     \
    if (sidx > SEQ - 8) sidx = SEQ - 8;                                         \
    const bfx8 vf0 = *(const bfx8*)(vb + (size_t)(li) * SEQ + sidx);            \
    const bfx8 vf1 = *(const bfx8*)(vb + (size_t)(16 + li) * SEQ + sidx);       \
    const bfx8 vf2 = *(const bfx8*)(vb + (size_t)(32 + li) * SEQ + sidx);       \
    const bfx8 vf3 = *(const bfx8*)(vb + (size_t)(48 + li) * SEQ + sidx);       \
    if (c + 1 < nc) {                                                           \
      const int j1 = j0 + 32;                                                   \
      int ja = j1 + li;      if (ja > SEQ - 1) ja = SEQ - 1;                    \
      int jb = j1 + 16 + li; if (jb > SEQ - 1) jb = SEQ - 1;                    \
      KFN[0] = *(const bfx8*)(kb + (size_t)ja * HDIM + lg * 8);                 \
      KFN[1] = *(const bfx8*)(kb + (size_t)ja * HDIM + 32 + lg * 8);            \
      KFN[2] = *(const bfx8*)(kb + (size_t)jb * HDIM + lg * 8);                 \
      KFN[3] = *(const bfx8*)(kb + (size_t)jb * HDIM + 32 + lg * 8);            \
    }                                                                           \
    f32x4 s0 = zero, s1 = zero;                                                 \
    s0 = MFMA16(qa[0], KFC[0], s0);                                             \
    s0 = MFMA16(qa[1], KFC[1], s0);                                             \
    s1 = MFMA16(qa[0], KFC[2], s1);                                             \
    s1 = MFMA16(qa[1], KFC[3], s1);                                             \
    const bool interior = (j0 >= i0 + 15 - half) && (j0 + 31 <= i0 + half) &&   \
                          (j0 + 31 <= SEQ - 1);                                 \
    if (interior) {                                                             \
      _Pragma("unroll") for (int r = 0; r < 4; ++r) {                           \
        const float p0 = exp2f(s0[r] * SCL);                                    \
        const float p1 = exp2f(s1[r] * SCL);                                    \
        lr[r] += p0 + p1;                                                       \
        P[PAR][lg * 4 + r][li] = f2bf(p0);                                      \
        P[PAR][lg * 4 + r][16 + li] = f2bf(p1);                                 \
      }                                                                         \
    } else {                                                                    \
      _Pragma("unroll") for (int r = 0; r < 4; ++r) {                           \
        const int i = i0 + lg * 4 + r;                                          \
        const int ja = j0 + li, jb = j0 + 16 + li;                              \
        int da = i - ja; if (da < 0) da = -da;                                  \
        int db = i - jb; if (db < 0) db = -db;                                  \
        const bool oka = (ja <= SEQ - 1) && (da <= half || ja == 0);            \
        const bool okb = (jb <= SEQ - 1) && (db <= half);                       \
        const float p0 = exp2f(fmaf(s0[r], SCL, oka ? 0.f : -1e5f));            \
        const float p1 = exp2f(fmaf(s1[r], SCL, okb ? 0.f : -1e5f));            \
        lr[r] += p0 + p1;                                                       \
        P[PAR][lg * 4 + r][li] = f2bf(p0);                                      \
        P[PAR][lg * 4 + r][16 + li] = f2bf(p1);                                 \
      }                                                                         \
    }                                                                           \
    const bfx8 pa = *(const bfx8*)(&P[PAR][li][lg * 8]);                        \
    ctxa[0] = MFMA16(pa, vf0, ctxa[0]);                                         \
    ctxa[1] = MFMA16(pa, vf1, ctxa[1]);                                         \
    ctxa[2] = MFMA16(pa, vf2, ctxa[2]);                                         \
    ctxa[3] = MFMA16(pa, vf3, ctxa[3]);                                         \
  }

__global__ __launch_bounds__(64) void attn_kernel(
    const u16* __restrict__ q, const u16* __restrict__ k,
    const u16* __restrict__ vt, u16* __restrict__ ctx,
    const int* __restrict__ wsz) {
  const int lane = threadIdx.x;
  const int li = lane & 15, lg = lane >> 4;
  const int bid = blockIdx.x;
  const int wid = (bid & 7) * 512 + (bid >> 3);
  const int qt = wid & 127;
  const int h = (wid >> 7) & 15;
  const int b = wid >> 11;
  const int i0 = qt * 16;
  const int bh = b * HEADS + h;
  const int half = wsz[0] >> 1;
  const float SCL = 0.125f * LOG2E;

  __shared__ alignas(16) u16 P[2][16][40];

  const u16* qb = q + (size_t)bh * SEQ * HDIM;
  const u16* kb = k + (size_t)bh * SEQ * HDIM;
  const u16* vb = vt + (size_t)bh * HDIM * SEQ;

  bfx8 qa[2];
#pragma unroll
  for (int ks = 0; ks < 2; ++ks)
    qa[ks] = *(const bfx8*)(qb + (size_t)(i0 + li) * HDIM + ks * 32 + lg * 8);

  int wlo = i0 - half; if (wlo < 0) wlo = 0; wlo &= ~31;
  int whi = i0 + 15 + half; if (whi > SEQ - 1) whi = SEQ - 1;
  const int nc = ((whi - wlo) >> 5) + 1;

  float lr[4] = {0.f, 0.f, 0.f, 0.f};
  f32x4 ctxa[4];
  const f32x4 zero = {0.f, 0.f, 0.f, 0.f};
#pragma unroll
  for (int dt = 0; dt < 4; ++dt) ctxa[dt] = zero;

  bfx8 kfA[4], kfB[4];
  {
    int ja = wlo + li;      if (ja > SEQ - 1) ja = SEQ - 1;
    int jb = wlo + 16 + li; if (jb > SEQ - 1) jb = SEQ - 1;
    kfA[0] = *(const bfx8*)(kb + (size_t)ja * HDIM + lg * 8);
    kfA[1] = *(const bfx8*)(kb + (size_t)ja * HDIM + 32 + lg * 8);
    kfA[2] = *(const bfx8*)(kb + (size_t)jb * HDIM + lg * 8);
    kfA[3] = *(const bfx8*)(kb + (size_t)jb * HDIM + 32 + lg * 8);
  }

  int c = 0;
  while (true) {
    ATTN_STEP(kfA, kfB, 0); if (++c >= nc) break;
    ATTN_STEP(kfB, kfA, 1); if (++c >= nc) break;
  }

#pragma unroll
  for (int r = 0; r < 4; ++r) {
    lr[r] += __shfl_xor(lr[r], 1);
    lr[r] += __shfl_xor(lr[r], 2);
    lr[r] += __shfl_xor(lr[r], 4);
    lr[r] += __shfl_xor(lr[r], 8);
  }

  if (wlo > 0) {
    const bfx8 k0a = *(const bfx8*)(kb + lg * 8);
    const bfx8 k0b = *(const bfx8*)(kb + 32 + lg * 8);
    float sg = 0.f;
#pragma unroll
    for (int e = 0; e < 8; ++e)
      sg += (float)qa[0][e] * (float)k0a[e] + (float)qa[1][e] * (float)k0b[e];
    sg += __shfl_xor(sg, 16);
    sg += __shfl_xor(sg, 32);
    const float pg = exp2f(sg * SCL);
    float v0[4];
#pragma unroll
    for (int dt = 0; dt < 4; ++dt) v0[dt] = bf2f(vb[(size_t)(dt * 16 + li) * SEQ]);
#pragma unroll
    for (int r = 0; r < 4; ++r) {
      const float pq = __shfl(pg, lg * 4 + r);
      lr[r] += pq;
#pragma unroll
      for (int dt = 0; dt < 4; ++dt) ctxa[dt][r] += pq * v0[dt];
    }
  }

#pragma unroll
  for (int r = 0; r < 4; ++r) {
    const float inv = 1.0f / lr[r];
    const int i = i0 + lg * 4 + r;
    const size_t base = ((size_t)b * SEQ + i) * HIDDEN + h * HDIM;
#pragma unroll
    for (int dt = 0; dt < 4; ++dt)
      ctx[base + dt * 16 + li] = f2bf(ctxa[dt][r] * inv);
  }
}

extern "C" void kernel_launch(void* const* d_in, const int* in_sizes, int n_in,
                              void* d_out, int out_size, void* d_ws, size_t ws_size,
                              hipStream_t stream) {
  const float* hs = (const float*)d_in[0];
  const float* Wq = (const float*)d_in[1];
  const float* bq = (const float*)d_in[2];
  const float* Wk = (const float*)d_in[3];
  const float* bk = (const float*)d_in[4];
  const float* Wv = (const float*)d_in[5];
  const float* bv = (const float*)d_in[6];
  const float* Wo = (const float*)d_in[7];
  const float* bo = (const float*)d_in[8];
  const int* wsz  = (const int*)d_in[9];
  float* out = (float*)d_out;

  const int BS = in_sizes[0] / HIDDEN;  // B*S = 4096
  (void)n_in; (void)out_size;

  u16* ws    = (u16*)d_ws;
  u16* hsb   = ws;                                  // [BS][1024] (reused as ctx)
  u16* wqkvt = hsb + (size_t)BS * HIDDEN;           // [3072][1024]
  u16* wot   = wqkvt + (size_t)3 * HIDDEN * HIDDEN; // [1024][1024]
  u16* qb    = wot + (size_t)HIDDEN * HIDDEN;       // [B*H][S][64]
  u16* kb    = qb + (size_t)BS * HIDDEN;
  u16* vtb   = kb + (size_t)BS * HIDDEN;            // [B*H][64][S]
  u16* vtmp  = vtb + (size_t)BS * HIDDEN;           // [B*H][S][64] (if ws allows)
  u16* ctxb  = hsb;

  const size_t need = ((size_t)4 * BS * HIDDEN + (size_t)4 * HIDDEN * HIDDEN +
                       (size_t)BS * HIDDEN) * sizeof(u16);
  const int vmode = (ws_size >= need) ? 1 : 0;   // deterministic per-harness

  cast_bf16_kernel<<<dim3(1024), dim3(256), 0, stream>>>(hs, hsb, BS * HIDDEN / 4);
  transpose_cast4_kernel<<<dim3(16, 16, 4), dim3(256), 0, stream>>>(Wq, Wk, Wv, Wo, wqkvt);

  gemm_qkv_kernel<<<dim3(24, 32), dim3(256), 0, stream>>>(
      hsb, wqkvt, bq, bk, bv, qb, kb, vmode ? vtmp : vtb, vmode);

  if (vmode)
    vtrans_kernel<<<dim3(SEQ / 64, BS / SEQ * HEADS), dim3(256), 0, stream>>>(vtmp, vtb);

  attn_kernel<<<dim3(4096), dim3(64), 0, stream>>>(qb, kb, vtb, ctxb, wsz);

  gemm_out_kernel<<<dim3(16, 32), dim3(256), 0, stream>>>(ctxb, wot, bo, out);
}